// Round 3
// baseline (479.097 us; speedup 1.0000x reference)
//
#include <hip/hip_runtime.h>

#define NELEM 20000000
#define BSEG  16384

// ws layout: [0 .. BSEG-1] seg_in (f32), [BSEG .. 2*BSEG-1] seg_tg (f32),
// then one double elem-loss accumulator (8B aligned).
#define WS_BYTES (2 * BSEG * 4 + 8)

__global__ __launch_bounds__(256) void main_pass(
        const float* __restrict__ in, const float* __restrict__ tg,
        const int* __restrict__ batch,
        float* __restrict__ seg_in, float* __restrict__ seg_tg,
        double* __restrict__ elem_acc, int n)
{
    const int tid = blockIdx.x * blockDim.x + threadIdx.x;
    const long long i0 = (long long)tid * 8;
    float elem = 0.0f;

    if (i0 < n) {  // N divisible by 8, so a live thread always has a full chunk
        const float4* in4 = reinterpret_cast<const float4*>(in + i0);
        const float4* tg4 = reinterpret_cast<const float4*>(tg + i0);
        const int4*   b4  = reinterpret_cast<const int4*>(batch + i0); // 8 x i32 = 32B

        float4 a0 = in4[0], a1 = in4[1];
        float4 t0 = tg4[0], t1 = tg4[1];
        int4   c0 = b4[0],  c1 = b4[1];

        float vi[8] = {a0.x, a0.y, a0.z, a0.w, a1.x, a1.y, a1.z, a1.w};
        float vt[8] = {t0.x, t0.y, t0.z, t0.w, t1.x, t1.y, t1.z, t1.w};
        int   vb[8] = {c0.x, c0.y, c0.z, c0.w, c1.x, c1.y, c1.z, c1.w};

        int   cur = vb[0];
        float si = 0.0f, st = 0.0f;
        bool  multi = false;

        #pragma unroll
        for (int j = 0; j < 8; ++j) {
            float x = vi[j], y = vt[j];
            float d = fabsf(x) - fabsf(y);
            elem = fmaf(d, d, elem);
            int b = vb[j];
            if (b != cur) {             // segment boundary inside this chunk (rare)
                atomicAdd(seg_in + cur, si);
                atomicAdd(seg_tg + cur, st);
                cur = b; si = 0.0f; st = 0.0f;
                multi = true;
            }
            si += x; st += y;
        }

        // Wave-level aggregation: sorted batch (avg seg len ~1220 >> 512
        // elements/wave) => usually the whole wave shares one segment id.
        unsigned long long act = __ballot(1);
        int  first   = __shfl(cur, 0);
        bool uniform = __all((!multi) && (cur == first));
        if (uniform && act == ~0ULL) {
            #pragma unroll
            for (int off = 32; off; off >>= 1) {
                si += __shfl_xor(si, off);
                st += __shfl_xor(st, off);
            }
            if ((threadIdx.x & 63) == 0) {
                atomicAdd(seg_in + cur, si);
                atomicAdd(seg_tg + cur, st);
            }
        } else {
            atomicAdd(seg_in + cur, si);
            atomicAdd(seg_tg + cur, st);
        }
    }

    // block-reduce elementwise loss (all 256 threads participate)
    #pragma unroll
    for (int off = 32; off; off >>= 1) elem += __shfl_xor(elem, off);
    __shared__ float wsum[4];
    int lane = threadIdx.x & 63, wid = threadIdx.x >> 6;
    if (lane == 0) wsum[wid] = elem;
    __syncthreads();
    if (threadIdx.x == 0) {
        float s = wsum[0] + wsum[1] + wsum[2] + wsum[3];
        atomicAdd(elem_acc, (double)s);
    }
}

__global__ __launch_bounds__(1024) void finalize_kernel(
        const float* __restrict__ seg_in, const float* __restrict__ seg_tg,
        const double* __restrict__ elem_acc, float* __restrict__ out)
{
    double acc = 0.0;
    for (int i = threadIdx.x; i < BSEG; i += 1024) {
        float a = seg_in[i], b = seg_tg[i];
        float d = a * a - b * b;           // f32 like the reference
        acc += (double)d * (double)d;
    }
    #pragma unroll
    for (int off = 32; off; off >>= 1) acc += __shfl_xor(acc, off);
    __shared__ double wsum[16];
    int lane = threadIdx.x & 63, wid = threadIdx.x >> 6;
    if (lane == 0) wsum[wid] = acc;
    __syncthreads();
    if (threadIdx.x == 0) {
        double t = 0.0;
        #pragma unroll
        for (int w = 0; w < 16; ++w) t += wsum[w];
        out[0] = (float)(t + *elem_acc);
    }
}

extern "C" void kernel_launch(void* const* d_in, const int* in_sizes, int n_in,
                              void* d_out, int out_size, void* d_ws, size_t ws_size,
                              hipStream_t stream) {
    const float* in    = (const float*)d_in[0];
    const float* tg    = (const float*)d_in[1];
    const int*   batch = (const int*)d_in[2];
    const int n = in_sizes[0];

    float*  seg_in   = (float*)d_ws;
    float*  seg_tg   = seg_in + BSEG;
    double* elem_acc = (double*)(seg_in + 2 * BSEG);
    float*  out      = (float*)d_out;

    hipMemsetAsync(d_ws, 0, WS_BYTES, stream);

    const int nthreads = n / 8;                       // N divisible by 8
    const int blocks   = (nthreads + 255) / 256;
    main_pass<<<blocks, 256, 0, stream>>>(in, tg, batch, seg_in, seg_tg, elem_acc, n);

    finalize_kernel<<<1, 1024, 0, stream>>>(seg_in, seg_tg, elem_acc, out);
}

// Round 5
// 232.400 us; speedup vs baseline: 2.0615x; 2.0615x over previous
//
#include <hip/hip_runtime.h>

#define BSEG  16384
#define NPART 256
// ws layout: seg_in[BSEG] f32, seg_tg[BSEG] f32, elem_part[NPART] f64
#define WS_BYTES (2 * BSEG * 4 + NPART * 8)

__global__ __launch_bounds__(256) void main_pass(
        const float* __restrict__ in, const float* __restrict__ tg,
        const int* __restrict__ batch,
        float* __restrict__ seg_in, float* __restrict__ seg_tg,
        double* __restrict__ elem_part, int n)
{
    const int tid  = blockIdx.x * blockDim.x + threadIdx.x;
    const int lane = threadIdx.x & 63;
    const long long i0 = (long long)tid * 8;

    float elem = 0.0f;
    int   cur  = -1;          // dead lanes: id -1, zero sums (scan-safe)
    float si = 0.0f, st = 0.0f;

    if (i0 < n) {  // N divisible by 8 => live threads have full chunks
        const float4* in4 = reinterpret_cast<const float4*>(in + i0);
        const float4* tg4 = reinterpret_cast<const float4*>(tg + i0);
        const int4*   b4  = reinterpret_cast<const int4*>(batch + i0);

        float4 a0 = in4[0], a1 = in4[1];
        float4 t0 = tg4[0], t1 = tg4[1];
        int4   c0 = b4[0],  c1 = b4[1];

        float vi[8] = {a0.x, a0.y, a0.z, a0.w, a1.x, a1.y, a1.z, a1.w};
        float vt[8] = {t0.x, t0.y, t0.z, t0.w, t1.x, t1.y, t1.z, t1.w};
        int   vb[8] = {c0.x, c0.y, c0.z, c0.w, c1.x, c1.y, c1.z, c1.w};

        cur = vb[0];
        #pragma unroll
        for (int j = 0; j < 8; ++j) {
            float x = vi[j], y = vt[j];
            float d = fabsf(x) - fabsf(y);
            elem = fmaf(d, d, elem);
            int b = vb[j];
            if (b != cur) {           // interior boundary (rare, ~0.65% threads):
                atomicAdd(seg_in + cur, si);   // flush completed run directly
                atomicAdd(seg_tg + cur, st);   // (distinct segments => depth ~1)
                cur = b; si = 0.0f; st = 0.0f;
            }
            si += x; st += y;
        }
    }

    // --- wave-level segmented inclusive scan over trailing runs ---
    // ids are non-decreasing across lanes (batch sorted, lane order = memory
    // order). One atomic pair per distinct run per wave instead of per lane.
    int prevId = __shfl_up(cur, 1);
    int f = (lane == 0) || (prevId != cur);
    #pragma unroll
    for (int d = 1; d < 64; d <<= 1) {
        float o1 = __shfl_up(si, d);
        float o2 = __shfl_up(st, d);
        int   of = __shfl_up(f,  d);
        if (lane >= d) {
            if (!f) { si += o1; st += o2; }
            f |= of;
        }
    }
    int nextId = __shfl_down(cur, 1);
    bool isTail = (lane == 63) || (nextId != cur);
    if (isTail && cur >= 0) {
        atomicAdd(seg_in + cur, si);
        atomicAdd(seg_tg + cur, st);
    }

    // --- block-reduce elementwise loss -> 256 partial slots (not 1!) ---
    #pragma unroll
    for (int off = 32; off; off >>= 1) elem += __shfl_xor(elem, off);
    __shared__ float wsum[4];
    int wid = threadIdx.x >> 6;
    if (lane == 0) wsum[wid] = elem;
    __syncthreads();
    if (threadIdx.x == 0) {
        float s = wsum[0] + wsum[1] + wsum[2] + wsum[3];
        atomicAdd(elem_part + (blockIdx.x & (NPART - 1)), (double)s);
    }
}

__global__ __launch_bounds__(1024) void finalize_kernel(
        const float* __restrict__ seg_in, const float* __restrict__ seg_tg,
        const double* __restrict__ elem_part, float* __restrict__ out)
{
    double acc = 0.0;
    for (int i = threadIdx.x; i < BSEG; i += 1024) {
        float a = seg_in[i], b = seg_tg[i];
        float d = a * a - b * b;           // f32 like the reference
        acc += (double)d * (double)d;
    }
    if (threadIdx.x < NPART) acc += elem_part[threadIdx.x];
    #pragma unroll
    for (int off = 32; off; off >>= 1) acc += __shfl_xor(acc, off);
    __shared__ double wsum[16];
    int lane = threadIdx.x & 63, wid = threadIdx.x >> 6;
    if (lane == 0) wsum[wid] = acc;
    __syncthreads();
    if (threadIdx.x == 0) {
        double t = 0.0;
        #pragma unroll
        for (int w = 0; w < 16; ++w) t += wsum[w];
        out[0] = (float)t;
    }
}

extern "C" void kernel_launch(void* const* d_in, const int* in_sizes, int n_in,
                              void* d_out, int out_size, void* d_ws, size_t ws_size,
                              hipStream_t stream) {
    const float* in    = (const float*)d_in[0];
    const float* tg    = (const float*)d_in[1];
    const int*   batch = (const int*)d_in[2];
    const int n = in_sizes[0];

    float*  seg_in    = (float*)d_ws;
    float*  seg_tg    = seg_in + BSEG;
    double* elem_part = (double*)(seg_in + 2 * BSEG);
    float*  out       = (float*)d_out;

    hipMemsetAsync(d_ws, 0, WS_BYTES, stream);

    const int nthreads = n / 8;
    const int blocks   = (nthreads + 255) / 256;
    main_pass<<<blocks, 256, 0, stream>>>(in, tg, batch, seg_in, seg_tg, elem_part, n);

    finalize_kernel<<<1, 1024, 0, stream>>>(seg_in, seg_tg, elem_part, out);
}